// Round 1
// baseline (154.889 us; speedup 1.0000x reference)
//
#include <hip/hip_runtime.h>
#include <hip/hip_bf16.h>

// ---------- types ----------
typedef __bf16 bf16x8 __attribute__((ext_vector_type(8)));
typedef float  floatx4 __attribute__((ext_vector_type(4)));

// ---------- helpers ----------
__device__ __forceinline__ __bf16 to_bf16(float f) {
    unsigned int u = __builtin_bit_cast(unsigned int, f);
    u += 0x7FFFu + ((u >> 16) & 1u);           // round-to-nearest-even
    unsigned short h = (unsigned short)(u >> 16);
    return __builtin_bit_cast(__bf16, h);
}

// Cayley sign for Cl(3,0): e_a * e_b = csign(a,b) * e_{a^b}
__host__ __device__ constexpr float csign(int a, int b) {
    int s = 0;
    for (int k = 1; k < 4; ++k) {
        int t = (a >> k) & b;
        s += (t & 1) + ((t >> 1) & 1) + ((t >> 2) & 1);
    }
    return (s & 1) ? -1.0f : 1.0f;
}

// rotor r: r[0]=scalar, r[1]=e12(idx3), r[2]=e13(idx5), r[3]=e23(idx6)
// x = r * s * reverse(r)
__device__ __forceinline__ void rotor_sandwich(const float r[4], const float s_in[8], float x[8]) {
    constexpr int RI[4] = {0, 3, 5, 6};
    float t[8];
#pragma unroll
    for (int k = 0; k < 8; ++k) t[k] = 0.f;
#pragma unroll
    for (int ia = 0; ia < 4; ++ia) {
#pragma unroll
        for (int jb = 0; jb < 8; ++jb) {
            t[RI[ia] ^ jb] += csign(RI[ia], jb) * r[ia] * s_in[jb];
        }
    }
    const float rr[4] = {r[0], -r[1], -r[2], -r[3]};  // reverse: grade-2 flips
#pragma unroll
    for (int k = 0; k < 8; ++k) x[k] = 0.f;
#pragma unroll
    for (int ka = 0; ka < 8; ++ka) {
#pragma unroll
        for (int ib = 0; ib < 4; ++ib) {
            x[ka ^ RI[ib]] += csign(ka, RI[ib]) * t[ka] * rr[ib];
        }
    }
}

__device__ __forceinline__ void rotor_from_bv(float b0, float b1, float b2, float r[4]) {
    float t2 = b0 * b0 + b1 * b1 + b2 * b2;
    float th = sqrtf(t2);
    float sc = (th > 1e-6f) ? (__sinf(th) / th) : 1.0f;
    r[0] = __cosf(th);
    r[1] = sc * b0;
    r[2] = sc * b1;
    r[3] = sc * b2;
}

// ---------- kernel ----------
// One wave per block. Wave handles 16 batch elements.
// lane l: owns b = blockIdx*16 + (l&15), channels c = (l>>4)*8 .. +7
// (this IS the MFMA 16x16x32 A-operand layout: A[m=lane&15][k=quad*8+j])
__global__ __launch_bounds__(64, 2) void dyn_kernel(
    const float* __restrict__ state, const int* __restrict__ action,
    const float* __restrict__ act_bv, const float* __restrict__ norm_scale,
    const float* __restrict__ rotor_bv, const float* __restrict__ lin_W,
    const float* __restrict__ lin_b, const float* __restrict__ reward_W,
    const float* __restrict__ reward_b,
    float* __restrict__ out_reward, float* __restrict__ out_next)
{
    const int lane = threadIdx.x;   // 0..63
    const int bl = lane & 15;       // local batch index (m / row in D)
    const int q  = lane >> 4;       // quad
    const int b  = blockIdx.x * 16 + bl;

    // h2 staging: layout [d][b*36 + o]; b-stride 36 keeps float4 reads 16B-aligned
    // and makes D-layout writes <=2-way bank aliased (free).
    __shared__ float h2s[8 * 16 * 36];

    // ---- action rotor (per lane; 4 lanes/b redundant, trivial) ----
    float r[4];
    {
        const int a = action[b];
        const float* p = act_bv + a * 3;
        rotor_from_bv(-0.5f * p[0], -0.5f * p[1], -0.5f * p[2], r);
    }

    // ---- load this lane's 8 state rows (256B contiguous per lane) ----
    const float* sp = state + ((size_t)b * 32 + (size_t)q * 8) * 8;
    float4 sv[8][2];
#pragma unroll
    for (int j = 0; j < 8; ++j) {
        sv[j][0] = ((const float4*)sp)[j * 2 + 0];
        sv[j][1] = ((const float4*)sp)[j * 2 + 1];
    }

    float  x[8][8];     // pre-linear sandwich output (kept fp32 for epilogue)
    bf16x8 afrag[8];    // A fragments: afrag[d][j] = h[c=q*8+j][d]

#pragma unroll
    for (int j = 0; j < 8; ++j) {
        const int c = q * 8 + j;
        float s_in[8] = {sv[j][0].x, sv[j][0].y, sv[j][0].z, sv[j][0].w,
                         sv[j][1].x, sv[j][1].y, sv[j][1].z, sv[j][1].w};
        float xv[8];
        rotor_sandwich(r, s_in, xv);

        float ss = 1e-6f;
#pragma unroll
        for (int d = 0; d < 8; ++d) ss += xv[d] * xv[d];
        float hscale = norm_scale[c] * rsqrtf(ss);
        float h0 = xv[0] * hscale;
        float gate = 0.5f * (1.0f + erff(h0 * 0.70710678118654752440f));
        float g2 = hscale * gate;

        float hv[8];
#pragma unroll
        for (int d = 0; d < 8; ++d) hv[d] = xv[d] * g2;

        // per-channel rotor sandwich
        float rc[4];
        {
            const float* rp = rotor_bv + c * 3;
            rotor_from_bv(-0.5f * rp[0], -0.5f * rp[1], -0.5f * rp[2], rc);
        }
        float hf[8];
        rotor_sandwich(rc, hv, hf);

#pragma unroll
        for (int d = 0; d < 8; ++d) {
            x[j][d] = xv[d];
            afrag[d][j] = to_bf16(hf[d]);
        }
    }

    // ---- B fragments (weights): B[k=i][n=o], lane holds i=q*8+j, o=bl(+16) ----
    // bfrag[g][half][j] = W[o][i][g], gathered via float4 (L2-hot)
    bf16x8 bfrag[4][2];
#pragma unroll
    for (int hh = 0; hh < 2; ++hh) {
        const int o = bl + 16 * hh;
#pragma unroll
        for (int j = 0; j < 8; ++j) {
            const int i = q * 8 + j;
            float4 w = ((const float4*)lin_W)[o * 32 + i];
            bfrag[0][hh][j] = to_bf16(w.x);
            bfrag[1][hh][j] = to_bf16(w.y);
            bfrag[2][hh][j] = to_bf16(w.z);
            bfrag[3][hh][j] = to_bf16(w.w);
        }
    }

    // ---- 16 MFMAs: h2[b(16), o(16), d] for both o-halves ----
    constexpr int GR[8] = {0, 1, 1, 2, 1, 2, 2, 3};  // grade(d)
    floatx4 acc[8][2];
#pragma unroll
    for (int d = 0; d < 8; ++d) {
#pragma unroll
        for (int hh = 0; hh < 2; ++hh) {
            floatx4 z = {0.f, 0.f, 0.f, 0.f};
            acc[d][hh] = __builtin_amdgcn_mfma_f32_16x16x32_bf16(
                afrag[d], bfrag[GR[d]][hh], z, 0, 0, 0);
        }
    }

    // lin_b adds to d=0 only (same o across the 4 row-regs)
#pragma unroll
    for (int hh = 0; hh < 2; ++hh) {
        const float lb = lin_b[bl + 16 * hh];
#pragma unroll
        for (int rg = 0; rg < 4; ++rg) acc[0][hh][rg] += lb;
    }

    // ---- D-layout (row=(l>>4)*4+reg, col=l&15) -> LDS ----
#pragma unroll
    for (int d = 0; d < 8; ++d) {
#pragma unroll
        for (int hh = 0; hh < 2; ++hh) {
            const int o = bl + 16 * hh;
#pragma unroll
            for (int rg = 0; rg < 4; ++rg) {
                const int row = q * 4 + rg;
                h2s[d * 576 + row * 36 + o] = acc[d][hh][rg];
            }
        }
    }
    __syncthreads();

    // ---- read back h2 in (b,c) layout, add into x ----
#pragma unroll
    for (int d = 0; d < 8; ++d) {
        const float* hp = &h2s[d * 576 + bl * 36 + q * 8];
        float4 ha = ((const float4*)hp)[0];
        float4 hb = ((const float4*)hp)[1];
        x[0][d] += ha.x; x[1][d] += ha.y; x[2][d] += ha.z; x[3][d] += ha.w;
        x[4][d] += hb.x; x[5][d] += hb.y; x[6][d] += hb.z; x[7][d] += hb.w;
    }

    // ---- store next_state (256B contiguous per lane) + reward reduction ----
    float* op = out_next + ((size_t)b * 32 + (size_t)q * 8) * 8;
    float rsum = 0.f;
#pragma unroll
    for (int j = 0; j < 8; ++j) {
        rsum += x[j][0] * reward_W[q * 8 + j];
        float4 o0 = {x[j][0], x[j][1], x[j][2], x[j][3]};
        float4 o1 = {x[j][4], x[j][5], x[j][6], x[j][7]};
        ((float4*)op)[j * 2 + 0] = o0;
        ((float4*)op)[j * 2 + 1] = o1;
    }
    // lanes {l, l+16, l+32, l+48} hold the 4 channel-quads of batch bl
    rsum += __shfl_xor(rsum, 16, 64);
    rsum += __shfl_xor(rsum, 32, 64);
    if (q == 0) out_reward[b] = rsum + reward_b[0];
}

// ---------- launch ----------
extern "C" void kernel_launch(void* const* d_in, const int* in_sizes, int n_in,
                              void* d_out, int out_size, void* d_ws, size_t ws_size,
                              hipStream_t stream) {
    const float* state      = (const float*)d_in[0];
    const int*   action     = (const int*)  d_in[1];
    const float* act_bv     = (const float*)d_in[2];
    const float* norm_scale = (const float*)d_in[3];
    const float* rotor_bv   = (const float*)d_in[4];
    const float* lin_W      = (const float*)d_in[5];
    const float* lin_b      = (const float*)d_in[6];
    const float* reward_W   = (const float*)d_in[7];
    const float* reward_b   = (const float*)d_in[8];

    float* out = (float*)d_out;
    const int B = in_sizes[1];           // action: (B,)
    float* out_reward = out;             // (B,1) flattened
    float* out_next   = out + B;         // (B,32,8) flattened

    dim3 grid(B / 16), block(64);
    hipLaunchKernelGGL(dyn_kernel, grid, block, 0, stream,
                       state, action, act_bv, norm_scale, rotor_bv,
                       lin_W, lin_b, reward_W, reward_b, out_reward, out_next);
    (void)n_in; (void)out_size; (void)d_ws; (void)ws_size;
}